// Round 11
// baseline (76.316 us; speedup 1.0000x reference)
//
#include <hip/hip_runtime.h>
#include <math.h>

// ChamferDistance: B=4, N=M=8192, 3-D fp32 points.
// out[0] = mean_i sqrt(min_j d2)*w  +  mean_j sqrt(min_i d2)
//
// MFMA formulation (R6+): d2 = qsq + (rsq - 2 q.r) as a K=5 dot on
// v_mfma_f32_32x32x16_f16 (32 refs x 32 queries = 1024 pairs/inst):
//   A (refs)    = (-2rx,-2ry,-2rz, rsq_hi, rsq_lo, 0,0,0) f16, lanes 0-31
//   B (queries) = (  qx,  qy,  qz,   1,      1,    0,0,0) f16, lanes 0-31
// lanes 32-63 (k=8..15) zero. D: col=lane&31=query; 16 regs x lane-half =
// 32 refs -> per-lane min3 fold + one shfl_xor(32). absmax 0.0 verified.
//
// R11: exact single-round residency. R7/R9/R10 all ran 2048 blocks (8/CU
// assigned) under a 6-waves/SIMD cap -> 6-resident round + 2-block tail
// ~= 2x a latency-bound wave pass; all three measured the same ~76us.
// Now: 4 query tiles/wave (QPW=128), grid (16,8,8)=1024 blocks = exactly
// 4 blocks/CU, __launch_bounds__(256,4) (VGPR cap 128, ~95 live, no
// spills). All 4096 waves co-resident, one round, zero tail.
// Epilogue: R10's partial-min stores (no memset, no atomics in nn).

#define EPS 1e-8f

typedef _Float16 f16x8 __attribute__((ext_vector_type(8)));
typedef float    f32x16 __attribute__((ext_vector_type(16)));

constexpr int B_    = 4;
constexpr int N_    = 8192;          // points per batch (N == M)
constexpr int TPB   = 256;           // 4 waves
constexpr int QPW   = 128;           // queries per wave (4 tiles of 32)
constexpr int QPB   = 4 * QPW;       // 512 queries per block
constexpr int RCH   = 8;             // ref chunks (grid.y)
constexpr int CHUNK = N_ / RCH;      // 1024 refs staged per block (16 KB)
constexpr int RB    = 64;            // reduce blocks

// grid: (N/QPB=16, RCH=8, 2*B=8) = 1024 blocks = 4/CU, all resident.
// part layout: part[(zb*RCH + c)*N + q]  (zb = dir*4+b), 2 MB total.
__global__ __launch_bounds__(TPB, 4)
void nn_mfma_kernel(const float* __restrict__ src, const float* __restrict__ tgt,
                    float* __restrict__ part, float* __restrict__ out)
{
    __shared__ f16x8 sref[CHUNK + 64];   // +64: zero slot & safe prefetch pad

    if (blockIdx.x == 0 && blockIdx.y == 0 && blockIdx.z == 0 && threadIdx.x == 0)
        out[0] = 0.f;                    // reduce (next dispatch) atomicAdds

    const int zb  = blockIdx.z;
    const int dir = zb >> 2;            // 0: src queries tgt, 1: tgt queries src
    const int b   = zb & 3;
    const float* Rraw = (dir ? src : tgt) + ((size_t)b * N_ + (size_t)blockIdx.y * CHUNK) * 3;
    const float* Qraw = (dir ? tgt : src) + (size_t)b * N_ * 3;
    float* opart = part + ((size_t)zb * RCH + blockIdx.y) * N_;

    const int tid = threadIdx.x;
    const _Float16 h0 = (_Float16)0.f;
    const _Float16 h1 = (_Float16)1.f;

    // stage + quantize refs inline: (-2x,-2y,-2z, rsq_hi, rsq_lo, 0,0,0)
    for (int k = tid; k < CHUNK; k += TPB) {
        const float* rp = Rraw + (size_t)k * 3;
        _Float16 hx = (_Float16)rp[0], hy = (_Float16)rp[1], hz = (_Float16)rp[2];
        float fx = (float)hx, fy = (float)hy, fz = (float)hz;
        float rsq = fx * fx + fy * fy + fz * fz;
        _Float16 rh = (_Float16)rsq;
        _Float16 rl = (_Float16)(rsq - (float)rh);
        f16x8 a = {(_Float16)(-2.f * fx), (_Float16)(-2.f * fy),
                   (_Float16)(-2.f * fz), rh, rl, h0, h0, h0};
        sref[k] = a;
    }
    if (tid < 64) {
        f16x8 z = {h0, h0, h0, h0, h0, h0, h0, h0};
        sref[CHUNK + tid] = z;
    }

    const int lane = tid & 63;
    const int wv   = tid >> 6;
    const int l31  = lane & 31;
    const int half = lane >> 5;          // 0: carries data (k=0..7), 1: zeros
    const int qb   = blockIdx.x * QPB + wv * QPW;

    // 4 B fragments quantized inline; lanes 32-63 stay zero (k=8..15)
    f16x8 Bq[4];
    float qs[4];
#pragma unroll
    for (int t = 0; t < 4; ++t) {
        Bq[t] = f16x8{h0, h0, h0, h0, h0, h0, h0, h0};
        qs[t] = 0.f;
    }
    if (half == 0) {
#pragma unroll
        for (int t = 0; t < 4; ++t) {
            const float* q = Qraw + (size_t)(qb + t * 32 + l31) * 3;
            _Float16 ax = (_Float16)q[0], ay = (_Float16)q[1], az = (_Float16)q[2];
            float fx = (float)ax, fy = (float)ay, fz = (float)az;
            Bq[t] = f16x8{ax, ay, az, h1, h1, h0, h0, h0};
            qs[t] = fx * fx + fy * fy + fz * fz;
        }
    }
    __syncthreads();

    const f32x16 zc = {};

    // K-loop: 1 ds_read_b128 feeds 4 independent MFMAs; folds interleaved so
    // >=2 MFMAs stay in flight while <=3 D tiles are live.
    int idx = (half == 0) ? l31 : CHUNK;
    const int step = (half == 0) ? 32 : 0;
    float mna[4] = {3.0e38f, 3.0e38f, 3.0e38f, 3.0e38f};
    float mnb[4] = {3.0e38f, 3.0e38f, 3.0e38f, 3.0e38f};

    f16x8 a = sref[idx];
    idx += step;
    for (int s = 0; s < CHUNK / 32; ++s) {
        f16x8 an = sref[idx];            // tail prefetch lands in pad (unused)
        idx += step;
        f32x16 d0 = __builtin_amdgcn_mfma_f32_32x32x16_f16(a, Bq[0], zc, 0, 0, 0);
        f32x16 d1 = __builtin_amdgcn_mfma_f32_32x32x16_f16(a, Bq[1], zc, 0, 0, 0);
#pragma unroll
        for (int r = 0; r < 8; r += 2)
            mna[0] = fminf(fminf(d0[r], d0[r + 1]), mna[0]);   // v_min3_f32
#pragma unroll
        for (int r = 8; r < 16; r += 2)
            mnb[0] = fminf(fminf(d0[r], d0[r + 1]), mnb[0]);
        f32x16 d2 = __builtin_amdgcn_mfma_f32_32x32x16_f16(a, Bq[2], zc, 0, 0, 0);
#pragma unroll
        for (int r = 0; r < 8; r += 2)
            mna[1] = fminf(fminf(d1[r], d1[r + 1]), mna[1]);
#pragma unroll
        for (int r = 8; r < 16; r += 2)
            mnb[1] = fminf(fminf(d1[r], d1[r + 1]), mnb[1]);
        f32x16 d3 = __builtin_amdgcn_mfma_f32_32x32x16_f16(a, Bq[3], zc, 0, 0, 0);
#pragma unroll
        for (int r = 0; r < 8; r += 2)
            mna[2] = fminf(fminf(d2[r], d2[r + 1]), mna[2]);
#pragma unroll
        for (int r = 8; r < 16; r += 2)
            mnb[2] = fminf(fminf(d2[r], d2[r + 1]), mnb[2]);
#pragma unroll
        for (int r = 0; r < 8; r += 2)
            mna[3] = fminf(fminf(d3[r], d3[r + 1]), mna[3]);
#pragma unroll
        for (int r = 8; r < 16; r += 2)
            mnb[3] = fminf(fminf(d3[r], d3[r + 1]), mnb[3]);
        a = an;
    }

#pragma unroll
    for (int t = 0; t < 4; ++t) {
        float mn = fminf(mna[t], mnb[t]);
        // rows split across lane halves: one xor-32 merge covers all 32 refs
        mn = fminf(mn, __shfl_xor(mn, 32));
        if (half == 0)
            opart[qb + t * 32 + l31] = fmaxf(mn + qs[t], 0.f);   // plain store
    }
}

// reduce: per query min over RCH partials -> sqrt -> weight -> sum ->
// atomicAdd into out[0] (zeroed by nn). 2 MB of partials, L2-resident.
__global__ __launch_bounds__(TPB)
void reduce_kernel(const float* __restrict__ part,
                   const float* __restrict__ w,
                   float* __restrict__ out)
{
    const int Q = 2 * B_ * N_;               // 65536 queries
    const float invBN = 1.0f / (float)(B_ * N_);

    float sum = 0.0f;
    for (int t = blockIdx.x * TPB + threadIdx.x; t < Q; t += RB * TPB) {
        const int zb = t >> 13;              // t / N_
        const int qn = t & (N_ - 1);
        const float* p = part + ((size_t)zb * RCH) * N_ + qn;
        float m = p[0];
#pragma unroll
        for (int c = 1; c < RCH; ++c) m = fminf(m, p[(size_t)c * N_]);
        float d = sqrtf(m + EPS);
        sum += (zb < 4) ? d * w[(size_t)zb * N_ + qn] : d;
    }
    sum *= invBN;

    __shared__ float ss[TPB / 64];
    int lane = threadIdx.x & 63;
    int wid  = threadIdx.x >> 6;
#pragma unroll
    for (int off = 32; off > 0; off >>= 1) sum += __shfl_down(sum, off);
    if (lane == 0) ss[wid] = sum;
    __syncthreads();
    if (threadIdx.x == 0) {
        float s = 0.0f;
#pragma unroll
        for (int i = 0; i < TPB / 64; ++i) s += ss[i];
        atomicAdd(out, s);
    }
}

extern "C" void kernel_launch(void* const* d_in, const int* in_sizes, int n_in,
                              void* d_out, int out_size, void* d_ws, size_t ws_size,
                              hipStream_t stream)
{
    const float* src = (const float*)d_in[0];   // (B, N, 3)
    const float* tgt = (const float*)d_in[1];   // (B, M, 3)
    const float* w   = (const float*)d_in[2];   // (B, N)
    float* out = (float*)d_out;

    float* part = (float*)d_ws;   // [2*B][RCH][N] = 2 MB, fully overwritten

    dim3 grid(N_ / QPB, RCH, 2 * B_);   // 16 x 8 x 8 = 1024 blocks
    nn_mfma_kernel<<<grid, TPB, 0, stream>>>(src, tgt, part, out);

    reduce_kernel<<<RB, TPB, 0, stream>>>(part, w, out);
}